// Round 6
// baseline (309.079 us; speedup 1.0000x reference)
//
#include <hip/hip_runtime.h>
#include <stdint.h>

#define T_SEQ 1024

typedef __attribute__((ext_vector_type(8))) short short8;
typedef __attribute__((ext_vector_type(4))) float f32x4;
typedef __attribute__((ext_vector_type(4))) unsigned short ushort4v;
typedef __attribute__((ext_vector_type(8))) unsigned short ushort8v;

__device__ __forceinline__ unsigned short f2bf(float f) {
  union { float f; uint32_t u; } v; v.f = f;
  return (unsigned short)((v.u + 0x7fffu + ((v.u >> 16) & 1u)) >> 16);
}
__device__ __forceinline__ float bf2f(unsigned short u) {
  union { uint32_t u; float f; } v; v.u = ((uint32_t)u) << 16;
  return v.f;
}

// async global->LDS, 16B per lane (m97 path; proven in-session R9/R10). Dest wave-uniform.
__device__ __forceinline__ void gl2lds16(const unsigned short* g, unsigned short* l) {
  __builtin_amdgcn_global_load_lds(
      (const __attribute__((address_space(1))) void*)g,
      (__attribute__((address_space(3))) void*)l, 16, 0, 0);
}

// ---------------- threefry2x32, JAX partitionable mode ----------------
__device__ __forceinline__ uint32_t tf_bits(uint32_t flat) {
  const uint32_t ks1 = 42u;
  const uint32_t ks2 = 0x1BD11BDAu ^ 42u;
  uint32_t x0 = 0u;
  uint32_t x1 = flat + ks1;
#define TFR(r) { x0 += x1; x1 = (x1 << (r)) | (x1 >> (32 - (r))); x1 ^= x0; }
  TFR(13) TFR(15) TFR(26) TFR(6)
  x0 += ks1; x1 += ks2 + 1u;
  TFR(17) TFR(29) TFR(16) TFR(24)
  x0 += ks2; x1 += 2u;
  TFR(13) TFR(15) TFR(26) TFR(6)
  x1 += ks1 + 3u;
  TFR(17) TFR(29) TFR(16) TFR(24)
  x0 += ks1; x1 += ks2 + 4u;
  TFR(13) TFR(15) TFR(26) TFR(6)
  x0 += ks2; x1 += 5u;
#undef TFR
  return x0 ^ x1;
}

__device__ __forceinline__ float gumbel_noise(uint32_t flat) {
  const uint32_t bits = tf_bits(flat);
  const float u = __uint_as_float((bits >> 9) | 0x3f800000u) - 1.0f;
  return -__logf(-__logf(u + 1e-20f) + 1e-20f);
}

// ---------------- pre-conversion pass: fp32 -> bf16 (plain, no split) ----------------
__global__ __launch_bounds__(256) void convert_pre(
    const float* __restrict__ g, const float* __restrict__ h,
    const float* __restrict__ wgi_f, const float* __restrict__ whi_f,
    const float* __restrict__ wgo_f, const float* __restrict__ who_f,
    unsigned short* __restrict__ gbf, unsigned short* __restrict__ hbf,
    unsigned short* __restrict__ wgi, unsigned short* __restrict__ whi,
    unsigned short* __restrict__ wgo, unsigned short* __restrict__ who)
{
  const int64_t Q_SPLIT = 1048576;              // (g 2M + h 2M) / 4
  const int64_t Q_TOTAL = Q_SPLIT + 1835008;    // + weights 7M / 4
  for (int64_t qd = (int64_t)blockIdx.x * 256 + threadIdx.x; qd < Q_TOTAL;
       qd += (int64_t)gridDim.x * 256) {
    if (qd < Q_SPLIT) {
      const int which = qd >= 524288;
      const int64_t e = (qd - (which ? 524288 : 0)) * 4;
      const float4 v = *(const float4*)((which ? h : g) + e);
      ushort4v u = {f2bf(v.x), f2bf(v.y), f2bf(v.z), f2bf(v.w)};
      *(ushort4v*)((which ? hbf : gbf) + e) = u;
    } else {
      int64_t off = qd - Q_SPLIT;
      const float* src; unsigned short* dst;
      if (off < 786432)                 { src = wgi_f; dst = wgi; }
      else if (off < 1310720)           { off -= 786432;  src = whi_f; dst = whi; }
      else if (off < 1572864)           { off -= 1310720; src = wgo_f; dst = wgo; }
      else                              { off -= 1572864; src = who_f; dst = who; }
      const int64_t e = off * 4;
      const float4 v = *(const float4*)(src + e);
      ushort4v u = {f2bf(v.x), f2bf(v.y), f2bf(v.z), f2bf(v.w)};
      *(ushort4v*)(dst + e) = u;
    }
  }
}

// ---------------- bf16 MFMA GEMM via global_load_lds (R9-proven) ----------------
template<int TM, bool BF16OUT>
__device__ __forceinline__ void gemm_plain_core(
    const unsigned short* __restrict__ Ab, const unsigned short* __restrict__ Wb,
    const float* __restrict__ bias, int N, int K, int m0, int n0,
    int scale_limit, void* Cout, unsigned short* sA, unsigned short* sW)
{
  const int tid = threadIdx.x;
  const int w = tid >> 6;
  const int lane = tid & 63;
  const int txl = lane & 15, q = lane >> 4;
  const int wr = (w >> 1) * (TM * 16);
  const int wc = (w & 1) << 6;
  const int lr = lane >> 3, lu = lane & 7;
  const int rx7 = txl & 7;

  const unsigned short* Asrc = Ab + (size_t)(m0 + w * 8 * TM + lr) * K + ((lu ^ lr) << 3);
  const unsigned short* Wsrc = Wb + (size_t)(n0 + w * 32 + lr) * K + ((lu ^ lr) << 3);
  unsigned short* sAd = sA + (w * 8 * TM) * 64;
  unsigned short* sWd = sW + (w * 32) * 64;

  f32x4 acc[TM][4];
#pragma unroll
  for (int i = 0; i < TM; i++)
#pragma unroll
    for (int j = 0; j < 4; j++) acc[i][j] = (f32x4){0.f, 0.f, 0.f, 0.f};

  for (int k0 = 0; k0 < K; k0 += 64) {
    __syncthreads();
#pragma unroll
    for (int i = 0; i < TM; i++)
      gl2lds16(Asrc + (size_t)(8 * i) * K + k0, sAd + (8 * i) * 64);
#pragma unroll
    for (int i = 0; i < 4; i++)
      gl2lds16(Wsrc + (size_t)(8 * i) * K + k0, sWd + (8 * i) * 64);
    __syncthreads();
#pragma unroll
    for (int kk = 0; kk < 2; kk++) {
      const int uoff = ((4 * kk + q) ^ rx7) << 3;
      short8 af[TM], wf[4];
#pragma unroll
      for (int i = 0; i < TM; i++)
        af[i] = *(const short8*)&sA[(wr + 16 * i + txl) * 64 + uoff];
#pragma unroll
      for (int j = 0; j < 4; j++)
        wf[j] = *(const short8*)&sW[(wc + 16 * j + txl) * 64 + uoff];
#pragma unroll
      for (int i = 0; i < TM; i++)
#pragma unroll
        for (int j = 0; j < 4; j++)
          acc[i][j] = __builtin_amdgcn_mfma_f32_16x16x32_bf16(af[i], wf[j], acc[i][j], 0, 0, 0);
    }
  }

#pragma unroll
  for (int j = 0; j < 4; j++) {
    const int col = n0 + wc + 16 * j + txl;
    const float bj = bias[col];
    const float sc = (col < scale_limit) ? 0.125f : 1.0f;
#pragma unroll
    for (int i = 0; i < TM; i++) {
      const int rbase = m0 + wr + 16 * i + 4 * q;
#pragma unroll
      for (int r = 0; r < 4; r++) {
        const float v = (acc[i][j][r] + bj) * sc;
        if (BF16OUT) ((unsigned short*)Cout)[(size_t)(rbase + r) * N + col] = f2bf(v);
        else         ((float*)Cout)[(size_t)(rbase + r) * N + col] = v;
      }
    }
  }
}

__global__ __launch_bounds__(256, 4) void gemm_inproj(
    const unsigned short* __restrict__ gbf, const unsigned short* __restrict__ wgi,
    const float* __restrict__ bgi,
    const unsigned short* __restrict__ hbf, const unsigned short* __restrict__ whi,
    const float* __restrict__ bhi,
    unsigned short* __restrict__ qkv, unsigned short* __restrict__ hkv)
{
  __shared__ __align__(16) unsigned short sm[16384];
  const int bx = blockIdx.x;
  const int m0 = blockIdx.y * 128;
  if (bx < 24)
    gemm_plain_core<4, true>(gbf, wgi, bgi, 3072, 1024, m0, bx * 128, 1024,
                             qkv, sm, sm + 8192);
  else
    gemm_plain_core<4, true>(hbf, whi, bhi, 2048, 1024, m0, (bx - 24) * 128, 0,
                             hkv, sm, sm + 8192);
}

__global__ __launch_bounds__(256, 2) void gemm_outproj(
    const unsigned short* __restrict__ attnb,
    const unsigned short* __restrict__ wgo, const float* __restrict__ bgo,
    const unsigned short* __restrict__ who, const float* __restrict__ bho,
    float* __restrict__ out)
{
  __shared__ __align__(16) unsigned short sm[12288];
  const int m0 = blockIdx.y * 64;
  const unsigned short* Wp = (m0 < 2048) ? wgo : who;
  const float* bp = (m0 < 2048) ? bgo : bho;
  gemm_plain_core<2, false>(attnb, Wp, bp, 1024, 1024, m0, blockIdx.x * 128, 0,
                            out, sm, sm + 4096);
}

// ---------------- V pre-transpose: qkv/hkv V-thirds -> vT[b][d][t] (R10-proven) ----------------
__global__ __launch_bounds__(256) void transpose_v(
    const unsigned short* __restrict__ qkv, const unsigned short* __restrict__ hkv,
    unsigned short* __restrict__ vTg, unsigned short* __restrict__ vTh)
{
  __shared__ __align__(16) unsigned short sm[64 * 72];
  const int tid = threadIdx.x;
  const int t0 = blockIdx.x * 64;
  const int d0 = blockIdx.y * 64;
  const int zb = blockIdx.z;          // b + 2*stream
  const int b = zb & 1;
  const int strm = zb >> 1;
  const unsigned short* src = strm ? hkv : qkv;
  const int srcoff = strm ? 1024 : 2048;
  const int sstride = strm ? 2048 : 3072;
  unsigned short* dst = strm ? vTh : vTg;

  const int r = tid >> 2, cs = (tid & 3) << 4;
  {
    const size_t gsrc = (size_t)((t0 + r) * 2 + b) * sstride + srcoff + d0 + cs;
    *(ushort8v*)&sm[r * 72 + cs]     = *(const ushort8v*)&src[gsrc];
    *(ushort8v*)&sm[r * 72 + cs + 8] = *(const ushort8v*)&src[gsrc + 8];
  }
  __syncthreads();
  const int dr = tid >> 2, ts = (tid & 3) << 4;
  ushort8v o0, o1;
#pragma unroll
  for (int m = 0; m < 8; m++) o0[m] = sm[(ts + m) * 72 + dr];
#pragma unroll
  for (int m = 0; m < 8; m++) o1[m] = sm[(ts + 8 + m) * 72 + dr];
  const size_t gdst = (size_t)b * 1048576 + (size_t)(d0 + dr) * 1024 + t0 + ts;
  *(ushort8v*)&dst[gdst]     = o0;
  *(ushort8v*)&dst[gdst + 8] = o1;
}

// ---------------- MFMA dual-stream attention, split-s partials ----------------
// R11: s-tile 32, separate K/V LDS buffers -> 2 barriers/iter; 25.6 KB LDS -> 6
// blocks/CU (24 waves). K+V both staged via global_load_lds right after barrier A,
// drained at B under ~1.3K cyc of gumbel. PC is wave-private (pack -> read ordered
// by lgkmcnt, no barrier). All swizzle algebra identical to R10-proven patterns:
// slot = logical_unit ^ (row&7), source pre-swizzled (rule #21). V^T rows pack
// g|h streams as units 0-3|4-7 -> same read XOR as K. T5 setprio around MFMA.
__global__ __launch_bounds__(256, 6) void attn_mfma(
    const unsigned short* __restrict__ qkv, const unsigned short* __restrict__ hkv,
    const unsigned short* __restrict__ vTg, const unsigned short* __restrict__ vTh,
    float* __restrict__ Opart, float* __restrict__ lpart)
{
  __shared__ __align__(16) unsigned short smem[12800];  // 25.6 KB
  unsigned short* KB = smem;          // Kg [32][64] @0, Kh [32][64] @2048
  unsigned short* VB = smem + 4096;   // V^T [64][64], units 0-3 = g, 4-7 = h
  unsigned short* PC = smem + 8192;   // 4 waves x 2 streams x [32][18]
  unsigned short* QS = smem;          // overlay (9216 shorts), pre-loop only

  const int tid = threadIdx.x;
  const int w = tid >> 6;
  const int lane = tid & 63;
  const int txl = lane & 15, q = lane >> 4;
  const int rx7 = txl & 7;
  const int lr = lane >> 3, lu = lane & 7;
  const int su = (lu ^ lr) << 3;      // K swizzled source col (shorts)
  const int lg_ = lu ^ lr;            // V logical unit for this lane's slot
  const int vsig = lg_ >> 2, vm = lg_ & 3;
  const int t0 = blockIdx.x * 64;
  const int bh = blockIdx.y;
  const int z = blockIdx.z;
  const int b = bh >> 4;
  const int head = bh & 15;
  const int hoff = head * 64;
  const int sr = tid >> 2;
  const int sc = (tid & 3) << 4;

  // ---- stage Q (pre-scaled bf16 from inproj) ----
  {
    const size_t gq = ((size_t)(t0 + sr) * 2 + b) * 3072 + hoff + sc;
    *(ushort8v*)&QS[sr * 72 + sc]     = *(const ushort8v*)&qkv[gq];
    *(ushort8v*)&QS[sr * 72 + sc + 8] = *(const ushort8v*)&qkv[gq + 8];
  }
  __syncthreads();
  const short8 aq0 = *(const short8*)&QS[(16 * w + txl) * 72 + 8 * q];
  const short8 aq1 = *(const short8*)&QS[(16 * w + txl) * 72 + 32 + 8 * q];

  f32x4 Og[4], Oh[4];
  float l_g[4], l_h[4];
#pragma unroll
  for (int i = 0; i < 4; i++) {
    Og[i] = (f32x4){0.f, 0.f, 0.f, 0.f};
    Oh[i] = (f32x4){0.f, 0.f, 0.f, 0.f};
    l_g[i] = 0.f; l_h[i] = 0.f;
  }

  unsigned short* pcg = PC + (w * 2 + 0) * 576;
  unsigned short* pch = PC + (w * 2 + 1) * 576;
  const unsigned short* vsrc = (vsig ? vTh : vTg) + (size_t)b * 1048576;

  const int s_begin = z * (T_SEQ / 2);
  const int s_end = s_begin + (T_SEQ / 2);
  for (int s0 = s_begin; s0 < s_end; s0 += 32) {
    __syncthreads();  // A: prev iter's K/V/PC reads complete
    // ---- issue K staging, both streams (1 gl2lds each per wave) ----
    {
      const size_t krow = (size_t)(s0 + w * 8 + lr) * 2 + b;
      gl2lds16(&qkv[krow * 3072 + 1024 + hoff + su], &KB[(w * 8) * 64]);
      gl2lds16(&hkv[krow * 2048 +        hoff + su], &KB[2048 + (w * 8) * 64]);
    }
    // ---- issue V^T staging (2 gl2lds per wave; per-lane stream select) ----
#pragma unroll
    for (int t = 0; t < 2; t++) {
      const int rb = w * 16 + 8 * t;
      gl2lds16(&vsrc[(size_t)(hoff + rb + lr) * 1024 + s0 + 8 * vm], &VB[rb * 64]);
    }
    // ---- gumbel noise (K/V-independent VALU) covers the load latency ----
    float ng[2][4];
#pragma unroll
    for (int nt = 0; nt < 2; nt++)
#pragma unroll
      for (int r = 0; r < 4; r++) {
        const uint32_t trow = (uint32_t)(t0 + 16 * w + 4 * q + r);
        const uint32_t scol_ = (uint32_t)(s0 + 16 * nt + txl);
        ng[nt][r] = gumbel_noise(((uint32_t)bh << 20) | (trow << 10) | scol_);
      }
    __syncthreads();  // B: drains vmcnt -> K and V both visible

    // ---- dual score GEMMs ----
    f32x4 Sg[2], Sh[2];
    const f32x4 zz = (f32x4){0.f, 0.f, 0.f, 0.f};
    const int u0 = (q ^ rx7) << 3;
    const int u1 = ((4 + q) ^ rx7) << 3;
    __builtin_amdgcn_s_setprio(1);
#pragma unroll
    for (int nt = 0; nt < 2; nt++) {
      const int srw = (16 * nt + txl) * 64;
      const short8 bg0 = *(const short8*)&KB[srw + u0];
      const short8 bg1 = *(const short8*)&KB[srw + u1];
      const short8 bh0 = *(const short8*)&KB[2048 + srw + u0];
      const short8 bh1 = *(const short8*)&KB[2048 + srw + u1];
      f32x4 ag = __builtin_amdgcn_mfma_f32_16x16x32_bf16(aq0, bg0, zz, 0, 0, 0);
      ag = __builtin_amdgcn_mfma_f32_16x16x32_bf16(aq1, bg1, ag, 0, 0, 0);
      f32x4 ah = __builtin_amdgcn_mfma_f32_16x16x32_bf16(aq0, bh0, zz, 0, 0, 0);
      ah = __builtin_amdgcn_mfma_f32_16x16x32_bf16(aq1, bh1, ah, 0, 0, 0);
      Sg[nt] = ag; Sh[nt] = ah;
    }
    __builtin_amdgcn_s_setprio(0);

    // ---- exp (noise from regs), partial l, pack P col-major (wave-private) ----
#pragma unroll
    for (int nt = 0; nt < 2; nt++) {
      float eg[4], eh[4];
#pragma unroll
      for (int r = 0; r < 4; r++) {
        eg[r] = __expf(Sg[nt][r]);             l_g[r] += eg[r];
        eh[r] = __expf(Sh[nt][r] + ng[nt][r]); l_h[r] += eh[r];
      }
      const int sbase = (16 * nt + txl) * 18 + 4 * q;
      *(uint32_t*)&pcg[sbase]     = (uint32_t)f2bf(eg[0]) | ((uint32_t)f2bf(eg[1]) << 16);
      *(uint32_t*)&pcg[sbase + 2] = (uint32_t)f2bf(eg[2]) | ((uint32_t)f2bf(eg[3]) << 16);
      *(uint32_t*)&pch[sbase]     = (uint32_t)f2bf(eh[0]) | ((uint32_t)f2bf(eh[1]) << 16);
      *(uint32_t*)&pch[sbase + 2] = (uint32_t)f2bf(eh[2]) | ((uint32_t)f2bf(eh[3]) << 16);
    }

    // ---- P-frag reads (same wave wrote them; lgkmcnt orders, no barrier) ----
    short8 apg, aph;
#pragma unroll
    for (int j = 0; j < 8; j++) {
      apg[j] = (short)pcg[(8 * q + j) * 18 + txl];
      aph[j] = (short)pch[(8 * q + j) * 18 + txl];
    }

    // ---- PV: O += P @ V (V ready since B) ----
    __builtin_amdgcn_s_setprio(1);
#pragma unroll
    for (int nt = 0; nt < 4; nt++) {
      const int drw = (16 * nt + txl) * 64;
      const short8 bvg = *(const short8*)&VB[drw + u0];
      const short8 bvh = *(const short8*)&VB[drw + u1];
      Og[nt] = __builtin_amdgcn_mfma_f32_16x16x32_bf16(apg, bvg, Og[nt], 0, 0, 0);
      Oh[nt] = __builtin_amdgcn_mfma_f32_16x16x32_bf16(aph, bvh, Oh[nt], 0, 0, 0);
    }
    __builtin_amdgcn_s_setprio(0);
  }

  // ---- epilogue: reduce l once, write unnormalized fp32 partials ----
  float* opg = Opart + ((size_t)(z * 2 + 0) * 2048) * 1024;
  float* oph = Opart + ((size_t)(z * 2 + 1) * 2048) * 1024;
  float* lpg = lpart + (size_t)(z * 2 + 0) * 2048 * 16;
  float* lph = lpart + (size_t)(z * 2 + 1) * 2048 * 16;
#pragma unroll
  for (int r = 0; r < 4; r++) {
    float lg = l_g[r], lh = l_h[r];
    lg += __shfl_xor(lg, 1); lg += __shfl_xor(lg, 2);
    lg += __shfl_xor(lg, 4); lg += __shfl_xor(lg, 8);
    lh += __shfl_xor(lh, 1); lh += __shfl_xor(lh, 2);
    lh += __shfl_xor(lh, 4); lh += __shfl_xor(lh, 8);
    const int row = (t0 + 16 * w + 4 * q + r) * 2 + b;
    if (txl == 0) {
      lpg[row * 16 + head] = lg;
      lph[row * 16 + head] = lh;
    }
    const size_t base = (size_t)row * 1024 + hoff;
#pragma unroll
    for (int nt = 0; nt < 4; nt++) {
      opg[base + 16 * nt + txl] = Og[nt][r];
      oph[base + 16 * nt + txl] = Oh[nt][r];
    }
  }
}

// ---------------- merge split-s partials -> bf16 attnb ----------------
__global__ __launch_bounds__(256) void merge_attn(
    const float* __restrict__ Opart, const float* __restrict__ lpart,
    unsigned short* __restrict__ attnb)
{
  const int idx = blockIdx.x * 256 + threadIdx.x;
  const int st = idx >> 19;
  const int i = idx & 0x7FFFF;
  const int row = i >> 8;
  const int colq = i & 255;
  const int head = colq >> 4;
  const float4 o0 = *(const float4*)&Opart[((size_t)(0 + st) * 2048 + row) * 1024 + colq * 4];
  const float4 o1 = *(const float4*)&Opart[((size_t)(2 + st) * 2048 + row) * 1024 + colq * 4];
  const float l0 = lpart[(size_t)(0 + st) * 32768 + row * 16 + head];
  const float l1 = lpart[(size_t)(2 + st) * 32768 + row * 16 + head];
  const float inv = 1.0f / (l0 + l1);
  ushort4v u = {f2bf((o0.x + o1.x) * inv), f2bf((o0.y + o1.y) * inv),
                f2bf((o0.z + o1.z) * inv), f2bf((o0.w + o1.w) * inv)};
  *(ushort4v*)&attnb[((size_t)st * 2048 + row) * 1024 + colq * 4] = u;
}

extern "C" void kernel_launch(void* const* d_in, const int* in_sizes, int n_in,
                              void* d_out, int out_size, void* d_ws, size_t ws_size,
                              hipStream_t stream) {
  const float* g       = (const float*)d_in[0];
  const float* h       = (const float*)d_in[1];
  const float* g_in_w  = (const float*)d_in[2];
  const float* g_in_b  = (const float*)d_in[3];
  const float* h_in_w  = (const float*)d_in[4];
  const float* h_in_b  = (const float*)d_in[5];
  const float* g_out_w = (const float*)d_in[6];
  const float* g_out_b = (const float*)d_in[7];
  const float* h_out_w = (const float*)d_in[8];
  const float* h_out_b = (const float*)d_in[9];
  float* out = (float*)d_out;

  unsigned short* ws = (unsigned short*)d_ws;
  // persistent region
  unsigned short* qkv   = ws;                        // [2048][3072] bf16
  unsigned short* hkv   = qkv + (size_t)2048*3072;   // [2048][2048]
  unsigned short* attnb = hkv + (size_t)2048*2048;   // [4096][1024]
  unsigned short* wgo   = attnb + (size_t)4096*1024; // [1024][1024]
  unsigned short* who   = wgo + (size_t)1024*1024;   // [1024][1024]
  // scratch: conversion buffers (dead after inproj) overlaid with attn partials
  unsigned short* scratch = who + (size_t)1024*1024;
  unsigned short* gbf = scratch;                     // [2048][1024]
  unsigned short* hbf = gbf + (size_t)2048*1024;     // [2048][1024]
  unsigned short* wgi = hbf + (size_t)2048*1024;     // [3072][1024]
  unsigned short* whi = wgi + (size_t)3072*1024;     // [2048][1024]
  float* Opart = (float*)scratch;                    // 4 planes x [2048][1024] fp32
  float* lpart = Opart + (size_t)4*2048*1024;        // 4 planes x [2048][16]
  // V^T planes, after the partials region (no overlap with Opart/lpart or conv bufs)
  unsigned short* vTg = (unsigned short*)(lpart + (size_t)4*2048*16);  // [2][1024][1024]
  unsigned short* vTh = vTg + (size_t)2*1024*1024;                     // [2][1024][1024]

  convert_pre<<<1024, 256, 0, stream>>>(g, h, g_in_w, h_in_w, g_out_w, h_out_w,
                                        gbf, hbf, wgi, whi, wgo, who);
  gemm_inproj<<<dim3(40, 16), 256, 0, stream>>>(
      gbf, wgi, g_in_b, hbf, whi, h_in_b, qkv, hkv);
  transpose_v<<<dim3(16, 16, 4), 256, 0, stream>>>(qkv, hkv, vTg, vTh);
  attn_mfma<<<dim3(T_SEQ / 64, 32, 2), 256, 0, stream>>>(qkv, hkv, vTg, vTh, Opart, lpart);
  merge_attn<<<4096, 256, 0, stream>>>(Opart, lpart, attnb);
  gemm_outproj<<<dim3(8, 64), 256, 0, stream>>>(
      attnb, wgo, g_out_b, who, h_out_b, out);
}

// Round 8
// 267.242 us; speedup vs baseline: 1.1566x; 1.1566x over previous
//
#include <hip/hip_runtime.h>
#include <stdint.h>

#define T_SEQ 1024

typedef __attribute__((ext_vector_type(8))) short short8;
typedef __attribute__((ext_vector_type(4))) float f32x4;
typedef __attribute__((ext_vector_type(4))) unsigned short ushort4v;
typedef __attribute__((ext_vector_type(8))) unsigned short ushort8v;

__device__ __forceinline__ unsigned short f2bf(float f) {
  union { float f; uint32_t u; } v; v.f = f;
  return (unsigned short)((v.u + 0x7fffu + ((v.u >> 16) & 1u)) >> 16);
}
__device__ __forceinline__ float bf2f(unsigned short u) {
  union { uint32_t u; float f; } v; v.u = ((uint32_t)u) << 16;
  return v.f;
}

// async global->LDS, 16B per lane (m97 path; proven in-session R9/R10). Dest wave-uniform.
__device__ __forceinline__ void gl2lds16(const unsigned short* g, unsigned short* l) {
  __builtin_amdgcn_global_load_lds(
      (const __attribute__((address_space(1))) void*)g,
      (__attribute__((address_space(3))) void*)l, 16, 0, 0);
}

// ---------------- threefry2x32, JAX partitionable mode ----------------
__device__ __forceinline__ uint32_t tf_bits(uint32_t flat) {
  const uint32_t ks1 = 42u;
  const uint32_t ks2 = 0x1BD11BDAu ^ 42u;
  uint32_t x0 = 0u;
  uint32_t x1 = flat + ks1;
#define TFR(r) { x0 += x1; x1 = (x1 << (r)) | (x1 >> (32 - (r))); x1 ^= x0; }
  TFR(13) TFR(15) TFR(26) TFR(6)
  x0 += ks1; x1 += ks2 + 1u;
  TFR(17) TFR(29) TFR(16) TFR(24)
  x0 += ks2; x1 += 2u;
  TFR(13) TFR(15) TFR(26) TFR(6)
  x1 += ks1 + 3u;
  TFR(17) TFR(29) TFR(16) TFR(24)
  x0 += ks1; x1 += ks2 + 4u;
  TFR(13) TFR(15) TFR(26) TFR(6)
  x0 += ks2; x1 += 5u;
#undef TFR
  return x0 ^ x1;
}

__device__ __forceinline__ float gumbel_noise(uint32_t flat) {
  const uint32_t bits = tf_bits(flat);
  const float u = __uint_as_float((bits >> 9) | 0x3f800000u) - 1.0f;
  return -__logf(-__logf(u + 1e-20f) + 1e-20f);
}

// ---------------- pre-conversion pass: fp32 -> bf16 (plain, no split) ----------------
__global__ __launch_bounds__(256) void convert_pre(
    const float* __restrict__ g, const float* __restrict__ h,
    const float* __restrict__ wgi_f, const float* __restrict__ whi_f,
    const float* __restrict__ wgo_f, const float* __restrict__ who_f,
    unsigned short* __restrict__ gbf, unsigned short* __restrict__ hbf,
    unsigned short* __restrict__ wgi, unsigned short* __restrict__ whi,
    unsigned short* __restrict__ wgo, unsigned short* __restrict__ who)
{
  const int64_t Q_SPLIT = 1048576;              // (g 2M + h 2M) / 4
  const int64_t Q_TOTAL = Q_SPLIT + 1835008;    // + weights 7M / 4
  for (int64_t qd = (int64_t)blockIdx.x * 256 + threadIdx.x; qd < Q_TOTAL;
       qd += (int64_t)gridDim.x * 256) {
    if (qd < Q_SPLIT) {
      const int which = qd >= 524288;
      const int64_t e = (qd - (which ? 524288 : 0)) * 4;
      const float4 v = *(const float4*)((which ? h : g) + e);
      ushort4v u = {f2bf(v.x), f2bf(v.y), f2bf(v.z), f2bf(v.w)};
      *(ushort4v*)((which ? hbf : gbf) + e) = u;
    } else {
      int64_t off = qd - Q_SPLIT;
      const float* src; unsigned short* dst;
      if (off < 786432)                 { src = wgi_f; dst = wgi; }
      else if (off < 1310720)           { off -= 786432;  src = whi_f; dst = whi; }
      else if (off < 1572864)           { off -= 1310720; src = wgo_f; dst = wgo; }
      else                              { off -= 1572864; src = who_f; dst = who; }
      const int64_t e = off * 4;
      const float4 v = *(const float4*)(src + e);
      ushort4v u = {f2bf(v.x), f2bf(v.y), f2bf(v.z), f2bf(v.w)};
      *(ushort4v*)(dst + e) = u;
    }
  }
}

// ---------------- bf16 MFMA GEMM via global_load_lds (R9-proven) ----------------
template<int TM, bool BF16OUT>
__device__ __forceinline__ void gemm_plain_core(
    const unsigned short* __restrict__ Ab, const unsigned short* __restrict__ Wb,
    const float* __restrict__ bias, int N, int K, int m0, int n0,
    int scale_limit, void* Cout, unsigned short* sA, unsigned short* sW)
{
  const int tid = threadIdx.x;
  const int w = tid >> 6;
  const int lane = tid & 63;
  const int txl = lane & 15, q = lane >> 4;
  const int wr = (w >> 1) * (TM * 16);
  const int wc = (w & 1) << 6;
  const int lr = lane >> 3, lu = lane & 7;
  const int rx7 = txl & 7;

  const unsigned short* Asrc = Ab + (size_t)(m0 + w * 8 * TM + lr) * K + ((lu ^ lr) << 3);
  const unsigned short* Wsrc = Wb + (size_t)(n0 + w * 32 + lr) * K + ((lu ^ lr) << 3);
  unsigned short* sAd = sA + (w * 8 * TM) * 64;
  unsigned short* sWd = sW + (w * 32) * 64;

  f32x4 acc[TM][4];
#pragma unroll
  for (int i = 0; i < TM; i++)
#pragma unroll
    for (int j = 0; j < 4; j++) acc[i][j] = (f32x4){0.f, 0.f, 0.f, 0.f};

  for (int k0 = 0; k0 < K; k0 += 64) {
    __syncthreads();
#pragma unroll
    for (int i = 0; i < TM; i++)
      gl2lds16(Asrc + (size_t)(8 * i) * K + k0, sAd + (8 * i) * 64);
#pragma unroll
    for (int i = 0; i < 4; i++)
      gl2lds16(Wsrc + (size_t)(8 * i) * K + k0, sWd + (8 * i) * 64);
    __syncthreads();
#pragma unroll
    for (int kk = 0; kk < 2; kk++) {
      const int uoff = ((4 * kk + q) ^ rx7) << 3;
      short8 af[TM], wf[4];
#pragma unroll
      for (int i = 0; i < TM; i++)
        af[i] = *(const short8*)&sA[(wr + 16 * i + txl) * 64 + uoff];
#pragma unroll
      for (int j = 0; j < 4; j++)
        wf[j] = *(const short8*)&sW[(wc + 16 * j + txl) * 64 + uoff];
#pragma unroll
      for (int i = 0; i < TM; i++)
#pragma unroll
        for (int j = 0; j < 4; j++)
          acc[i][j] = __builtin_amdgcn_mfma_f32_16x16x32_bf16(af[i], wf[j], acc[i][j], 0, 0, 0);
    }
  }

#pragma unroll
  for (int j = 0; j < 4; j++) {
    const int col = n0 + wc + 16 * j + txl;
    const float bj = bias[col];
    const float sc = (col < scale_limit) ? 0.125f : 1.0f;
#pragma unroll
    for (int i = 0; i < TM; i++) {
      const int rbase = m0 + wr + 16 * i + 4 * q;
#pragma unroll
      for (int r = 0; r < 4; r++) {
        const float v = (acc[i][j][r] + bj) * sc;
        if (BF16OUT) ((unsigned short*)Cout)[(size_t)(rbase + r) * N + col] = f2bf(v);
        else         ((float*)Cout)[(size_t)(rbase + r) * N + col] = v;
      }
    }
  }
}

__global__ __launch_bounds__(256, 4) void gemm_inproj(
    const unsigned short* __restrict__ gbf, const unsigned short* __restrict__ wgi,
    const float* __restrict__ bgi,
    const unsigned short* __restrict__ hbf, const unsigned short* __restrict__ whi,
    const float* __restrict__ bhi,
    unsigned short* __restrict__ qkv, unsigned short* __restrict__ hkv)
{
  __shared__ __align__(16) unsigned short sm[16384];
  const int bx = blockIdx.x;
  const int m0 = blockIdx.y * 128;
  if (bx < 24)
    gemm_plain_core<4, true>(gbf, wgi, bgi, 3072, 1024, m0, bx * 128, 1024,
                             qkv, sm, sm + 8192);
  else
    gemm_plain_core<4, true>(hbf, whi, bhi, 2048, 1024, m0, (bx - 24) * 128, 0,
                             hkv, sm, sm + 8192);
}

__global__ __launch_bounds__(256, 2) void gemm_outproj(
    const unsigned short* __restrict__ attnb,
    const unsigned short* __restrict__ wgo, const float* __restrict__ bgo,
    const unsigned short* __restrict__ who, const float* __restrict__ bho,
    float* __restrict__ out)
{
  __shared__ __align__(16) unsigned short sm[12288];
  const int m0 = blockIdx.y * 64;
  const unsigned short* Wp = (m0 < 2048) ? wgo : who;
  const float* bp = (m0 < 2048) ? bgo : bho;
  gemm_plain_core<2, false>(attnb, Wp, bp, 1024, 1024, m0, blockIdx.x * 128, 0,
                            out, sm, sm + 4096);
}

// ---------------- V pre-transpose: qkv/hkv V-thirds -> vT[b][d][t] (R10-proven) ----------------
__global__ __launch_bounds__(256) void transpose_v(
    const unsigned short* __restrict__ qkv, const unsigned short* __restrict__ hkv,
    unsigned short* __restrict__ vTg, unsigned short* __restrict__ vTh)
{
  __shared__ __align__(16) unsigned short sm[64 * 72];
  const int tid = threadIdx.x;
  const int t0 = blockIdx.x * 64;
  const int d0 = blockIdx.y * 64;
  const int zb = blockIdx.z;          // b + 2*stream
  const int b = zb & 1;
  const int strm = zb >> 1;
  const unsigned short* src = strm ? hkv : qkv;
  const int srcoff = strm ? 1024 : 2048;
  const int sstride = strm ? 2048 : 3072;
  unsigned short* dst = strm ? vTh : vTg;

  const int r = tid >> 2, cs = (tid & 3) << 4;
  {
    const size_t gsrc = (size_t)((t0 + r) * 2 + b) * sstride + srcoff + d0 + cs;
    *(ushort8v*)&sm[r * 72 + cs]     = *(const ushort8v*)&src[gsrc];
    *(ushort8v*)&sm[r * 72 + cs + 8] = *(const ushort8v*)&src[gsrc + 8];
  }
  __syncthreads();
  const int dr = tid >> 2, ts = (tid & 3) << 4;
  ushort8v o0, o1;
#pragma unroll
  for (int m = 0; m < 8; m++) o0[m] = sm[(ts + m) * 72 + dr];
#pragma unroll
  for (int m = 0; m < 8; m++) o1[m] = sm[(ts + 8 + m) * 72 + dr];
  const size_t gdst = (size_t)b * 1048576 + (size_t)(d0 + dr) * 1024 + t0 + ts;
  *(ushort8v*)&dst[gdst]     = o0;
  *(ushort8v*)&dst[gdst + 8] = o1;
}

// ---------------- MFMA dual-stream attention, split-s partials ----------------
// R13: R11's correctness-PASSED interior at s-tile 64, single-buffered (no dbuf —
// R12's race), spill-proof (256,3). Per iteration: barrier A; stage K AND V via
// 8 gl2lds/wave into separate buffers; gumbel (~1300 cy) covers BOTH drains;
// barrier B; QK -> exp/pack (wave-private PC) -> P-frag reads (lgkm-ordered, no
// barrier) -> PV. 2 barriers/iter vs R10's 4, zero exposed DMA latency.
// LDS: K 2x[64][64] 16KB + V^T 2x[64][64] 16KB + PC 18.4KB = 51.2KB -> 3 blocks/CU.
// Swizzle (proven): slot lu holds logical unit lu^lr; read unit U at row r from
// slot U^(r&7). Tripwire: WRITE_SIZE must stay ~46MB (spill detector).
__global__ __launch_bounds__(256, 3) void attn_mfma(
    const unsigned short* __restrict__ qkv, const unsigned short* __restrict__ hkv,
    const unsigned short* __restrict__ vTg, const unsigned short* __restrict__ vTh,
    float* __restrict__ Opart, float* __restrict__ lpart)
{
  __shared__ __align__(16) unsigned short smem[25600];  // 51.2 KB
  unsigned short* KB = smem;          // Kg[64][64] @0, Kh[64][64] @4096
  unsigned short* VB = smem + 8192;   // Vg^T[64][64] @0, Vh^T[64][64] @4096
  unsigned short* PC = smem + 16384;  // 4 waves x 2 streams x [64][18] = 9216
  unsigned short* QS = smem;          // overlay (4608 shorts), pre-loop only

  const int tid = threadIdx.x;
  const int w = tid >> 6;
  const int lane = tid & 63;
  const int txl = lane & 15, q = lane >> 4;
  const int rx7 = txl & 7;
  const int lr = lane >> 3, lu = lane & 7;
  const int su = (lu ^ lr) << 3;      // swizzled source unit offset (shorts)
  const int t0 = blockIdx.x * 64;
  const int bh = blockIdx.y;
  const int z = blockIdx.z;
  const int b = bh >> 4;
  const int head = bh & 15;
  const int hoff = head * 64;
  const int sr = tid >> 2;
  const int sc = (tid & 3) << 4;

  // ---- stage Q (pre-scaled bf16 from inproj) ----
  {
    const size_t gq = ((size_t)(t0 + sr) * 2 + b) * 3072 + hoff + sc;
    *(ushort8v*)&QS[sr * 72 + sc]     = *(const ushort8v*)&qkv[gq];
    *(ushort8v*)&QS[sr * 72 + sc + 8] = *(const ushort8v*)&qkv[gq + 8];
  }
  __syncthreads();
  const short8 aq0 = *(const short8*)&QS[(16 * w + txl) * 72 + 8 * q];
  const short8 aq1 = *(const short8*)&QS[(16 * w + txl) * 72 + 32 + 8 * q];

  f32x4 Og[4], Oh[4];
  float l_g[4], l_h[4];
#pragma unroll
  for (int i = 0; i < 4; i++) {
    Og[i] = (f32x4){0.f, 0.f, 0.f, 0.f};
    Oh[i] = (f32x4){0.f, 0.f, 0.f, 0.f};
    l_g[i] = 0.f; l_h[i] = 0.f;
  }

  unsigned short* pcg = PC + (w * 2 + 0) * 1152;
  unsigned short* pch = PC + (w * 2 + 1) * 1152;
  const unsigned short* vTgb = vTg + (size_t)b * 1048576;
  const unsigned short* vThb = vTh + (size_t)b * 1048576;

  const int u0 = (q ^ rx7) << 3;        // logical unit q
  const int u1 = ((4 + q) ^ rx7) << 3;  // logical unit 4+q
  const f32x4 zz = (f32x4){0.f, 0.f, 0.f, 0.f};

  const int s_begin = z * (T_SEQ / 2);
  const int s_end = s_begin + (T_SEQ / 2);
  for (int s0 = s_begin; s0 < s_end; s0 += 64) {
    __syncthreads();  // A: prev iter's K/V/PC reads complete (iter0: Q-frag reads)
    // ---- stage K and V, both streams (8 gl2lds per wave) ----
#pragma unroll
    for (int t = 0; t < 2; t++) {
      const int rb = w * 16 + 8 * t;
      const size_t krow = (size_t)(s0 + rb + lr) * 2 + b;
      gl2lds16(&qkv[krow * 3072 + 1024 + hoff + su], &KB[rb * 64]);
      gl2lds16(&hkv[krow * 2048 +        hoff + su], &KB[4096 + rb * 64]);
      const size_t vrow = (size_t)(hoff + rb + lr) * 1024 + s0 + su;
      gl2lds16(&vTgb[vrow], &VB[rb * 64]);
      gl2lds16(&vThb[vrow], &VB[4096 + rb * 64]);
    }
    // ---- gumbel noise (load-independent VALU) covers both DMA drains ----
    float ng[4][4];
#pragma unroll
    for (int nt = 0; nt < 4; nt++)
#pragma unroll
      for (int r = 0; r < 4; r++) {
        const uint32_t trow = (uint32_t)(t0 + 16 * w + 4 * q + r);
        const uint32_t scol_ = (uint32_t)(s0 + 16 * nt + txl);
        ng[nt][r] = gumbel_noise(((uint32_t)bh << 20) | (trow << 10) | scol_);
      }
    __syncthreads();  // B: drains vmcnt -> K and V both visible

    // ---- dual score GEMMs ----
    f32x4 Sg[4], Sh[4];
    __builtin_amdgcn_s_setprio(1);
#pragma unroll
    for (int nt = 0; nt < 4; nt++) {
      const int srw = (16 * nt + txl) * 64;
      const short8 bg0 = *(const short8*)&KB[srw + u0];
      const short8 bg1 = *(const short8*)&KB[srw + u1];
      const short8 bh0 = *(const short8*)&KB[4096 + srw + u0];
      const short8 bh1 = *(const short8*)&KB[4096 + srw + u1];
      f32x4 ag = __builtin_amdgcn_mfma_f32_16x16x32_bf16(aq0, bg0, zz, 0, 0, 0);
      ag = __builtin_amdgcn_mfma_f32_16x16x32_bf16(aq1, bg1, ag, 0, 0, 0);
      f32x4 ah = __builtin_amdgcn_mfma_f32_16x16x32_bf16(aq0, bh0, zz, 0, 0, 0);
      ah = __builtin_amdgcn_mfma_f32_16x16x32_bf16(aq1, bh1, ah, 0, 0, 0);
      Sg[nt] = ag; Sh[nt] = ah;
    }
    __builtin_amdgcn_s_setprio(0);

    // ---- exp (noise from regs), partial l, pack P col-major (wave-private) ----
#pragma unroll
    for (int nt = 0; nt < 4; nt++) {
      float eg[4], eh[4];
#pragma unroll
      for (int r = 0; r < 4; r++) {
        eg[r] = __expf(Sg[nt][r]);             l_g[r] += eg[r];
        eh[r] = __expf(Sh[nt][r] + ng[nt][r]); l_h[r] += eh[r];
      }
      const int sbase = (16 * nt + txl) * 18 + 4 * q;
      *(uint32_t*)&pcg[sbase]     = (uint32_t)f2bf(eg[0]) | ((uint32_t)f2bf(eg[1]) << 16);
      *(uint32_t*)&pcg[sbase + 2] = (uint32_t)f2bf(eg[2]) | ((uint32_t)f2bf(eg[3]) << 16);
      *(uint32_t*)&pch[sbase]     = (uint32_t)f2bf(eh[0]) | ((uint32_t)f2bf(eh[1]) << 16);
      *(uint32_t*)&pch[sbase + 2] = (uint32_t)f2bf(eh[2]) | ((uint32_t)f2bf(eh[3]) << 16);
    }

    // ---- P-frag reads (same wave wrote them; lgkmcnt orders, no barrier) ----
    short8 apg[2], aph[2];
#pragma unroll
    for (int c = 0; c < 2; c++)
#pragma unroll
      for (int j = 0; j < 8; j++) {
        apg[c][j] = (short)pcg[(32 * c + 8 * q + j) * 18 + txl];
        aph[c][j] = (short)pch[(32 * c + 8 * q + j) * 18 + txl];
      }

    // ---- PV: O += P @ V ----
    __builtin_amdgcn_s_setprio(1);
#pragma unroll
    for (int c = 0; c < 2; c++) {
      const int uv = (c == 0) ? u0 : u1;  // logical unit 4c+q
#pragma unroll
      for (int nt = 0; nt < 4; nt++) {
        const int drw = (16 * nt + txl) * 64;
        const short8 bvg = *(const short8*)&VB[drw + uv];
        const short8 bvh = *(const short8*)&VB[4096 + drw + uv];
        Og[nt] = __builtin_amdgcn_mfma_f32_16x16x32_bf16(apg[c], bvg, Og[nt], 0, 0, 0);
        Oh[nt] = __builtin_amdgcn_mfma_f32_16x16x32_bf16(aph[c], bvh, Oh[nt], 0, 0, 0);
      }
    }
    __builtin_amdgcn_s_setprio(0);
  }

  // ---- epilogue: reduce l once, write unnormalized fp32 partials ----
  float* opg = Opart + ((size_t)(z * 2 + 0) * 2048) * 1024;
  float* oph = Opart + ((size_t)(z * 2 + 1) * 2048) * 1024;
  float* lpg = lpart + (size_t)(z * 2 + 0) * 2048 * 16;
  float* lph = lpart + (size_t)(z * 2 + 1) * 2048 * 16;
#pragma unroll
  for (int r = 0; r < 4; r++) {
    float lg = l_g[r], lh = l_h[r];
    lg += __shfl_xor(lg, 1); lg += __shfl_xor(lg, 2);
    lg += __shfl_xor(lg, 4); lg += __shfl_xor(lg, 8);
    lh += __shfl_xor(lh, 1); lh += __shfl_xor(lh, 2);
    lh += __shfl_xor(lh, 4); lh += __shfl_xor(lh, 8);
    const int row = (t0 + 16 * w + 4 * q + r) * 2 + b;
    if (txl == 0) {
      lpg[row * 16 + head] = lg;
      lph[row * 16 + head] = lh;
    }
    const size_t base = (size_t)row * 1024 + hoff;
#pragma unroll
    for (int nt = 0; nt < 4; nt++) {
      opg[base + 16 * nt + txl] = Og[nt][r];
      oph[base + 16 * nt + txl] = Oh[nt][r];
    }
  }
}

// ---------------- merge split-s partials -> bf16 attnb ----------------
__global__ __launch_bounds__(256) void merge_attn(
    const float* __restrict__ Opart, const float* __restrict__ lpart,
    unsigned short* __restrict__ attnb)
{
  const int idx = blockIdx.x * 256 + threadIdx.x;
  const int st = idx >> 19;
  const int i = idx & 0x7FFFF;
  const int row = i >> 8;
  const int colq = i & 255;
  const int head = colq >> 4;
  const float4 o0 = *(const float4*)&Opart[((size_t)(0 + st) * 2048 + row) * 1024 + colq * 4];
  const float4 o1 = *(const float4*)&Opart[((size_t)(2 + st) * 2048 + row) * 1024 + colq * 4];
  const float l0 = lpart[(size_t)(0 + st) * 32768 + row * 16 + head];
  const float l1 = lpart[(size_t)(2 + st) * 32768 + row * 16 + head];
  const float inv = 1.0f / (l0 + l1);
  ushort4v u = {f2bf((o0.x + o1.x) * inv), f2bf((o0.y + o1.y) * inv),
                f2bf((o0.z + o1.z) * inv), f2bf((o0.w + o1.w) * inv)};
  *(ushort4v*)&attnb[((size_t)st * 2048 + row) * 1024 + colq * 4] = u;
}

extern "C" void kernel_launch(void* const* d_in, const int* in_sizes, int n_in,
                              void* d_out, int out_size, void* d_ws, size_t ws_size,
                              hipStream_t stream) {
  const float* g       = (const float*)d_in[0];
  const float* h       = (const float*)d_in[1];
  const float* g_in_w  = (const float*)d_in[2];
  const float* g_in_b  = (const float*)d_in[3];
  const float* h_in_w  = (const float*)d_in[4];
  const float* h_in_b  = (const float*)d_in[5];
  const float* g_out_w = (const float*)d_in[6];
  const float* g_out_b = (const float*)d_in[7];
  const float* h_out_w = (const float*)d_in[8];
  const float* h_out_b = (const float*)d_in[9];
  float* out = (float*)d_out;

  unsigned short* ws = (unsigned short*)d_ws;
  // persistent region
  unsigned short* qkv   = ws;                        // [2048][3072] bf16
  unsigned short* hkv   = qkv + (size_t)2048*3072;   // [2048][2048]
  unsigned short* attnb = hkv + (size_t)2048*2048;   // [4096][1024]
  unsigned short* wgo   = attnb + (size_t)4096*1024; // [1024][1024]
  unsigned short* who   = wgo + (size_t)1024*1024;   // [1024][1024]
  // scratch: conversion buffers (dead after inproj) overlaid with attn partials
  unsigned short* scratch = who + (size_t)1024*1024;
  unsigned short* gbf = scratch;                     // [2048][1024]
  unsigned short* hbf = gbf + (size_t)2048*1024;     // [2048][1024]
  unsigned short* wgi = hbf + (size_t)2048*1024;     // [3072][1024]
  unsigned short* whi = wgi + (size_t)3072*1024;     // [2048][1024]
  float* Opart = (float*)scratch;                    // 4 planes x [2048][1024] fp32
  float* lpart = Opart + (size_t)4*2048*1024;        // 4 planes x [2048][16]
  // V^T planes, after the partials region (no overlap with Opart/lpart or conv bufs)
  unsigned short* vTg = (unsigned short*)(lpart + (size_t)4*2048*16);  // [2][1024][1024]
  unsigned short* vTh = vTg + (size_t)2*1024*1024;                     // [2][1024][1024]

  convert_pre<<<1024, 256, 0, stream>>>(g, h, g_in_w, h_in_w, g_out_w, h_out_w,
                                        gbf, hbf, wgi, whi, wgo, who);
  gemm_inproj<<<dim3(40, 16), 256, 0, stream>>>(
      gbf, wgi, g_in_b, hbf, whi, h_in_b, qkv, hkv);
  transpose_v<<<dim3(16, 16, 4), 256, 0, stream>>>(qkv, hkv, vTg, vTh);
  attn_mfma<<<dim3(T_SEQ / 64, 32, 2), 256, 0, stream>>>(qkv, hkv, vTg, vTh, Opart, lpart);
  merge_attn<<<4096, 256, 0, stream>>>(Opart, lpart, attnb);
  gemm_outproj<<<dim3(8, 64), 256, 0, stream>>>(
      attnb, wgo, g_out_b, who, h_out_b, out);
}